// Round 1
// baseline (17157.664 us; speedup 1.0000x reference)
//
#include <hip/hip_runtime.h>
#include <math.h>

// Hierarchical RNN (SegRNN-like), MI355X fp32 baseline.
// N = B*ENC = 10272 GRU batch; layer0: 15 seq steps d=512; layer1: 60 seq steps d=256
// (input cycles over segments 0..3 only). Decoder = 1 gh GEMM + tiny gi + pointwise + proj.

#define NB     10272
#define ENC_   321
#define BATCH_ 32
#define SEQ_   720
#define PRED_  96

typedef long long i64;

__device__ __forceinline__ float sigmf(float x) { return 1.0f / (1.0f + expf(-x)); }

__global__ __launch_bounds__(256) void zero_kernel(float* __restrict__ p, int n) {
    int i = blockIdx.x * 256 + threadIdx.x;
    if (i < n) p[i] = 0.0f;
}

// seg[n*s + j] = x[b, t*s + j, e] - x[b, 719, e]   (n = b*ENC+e)
__global__ __launch_bounds__(256) void seg_gather(const float* __restrict__ x,
                                                  float* __restrict__ seg,
                                                  int t, int s) {
    int idx = blockIdx.x * 256 + threadIdx.x;
    int total = NB * s;
    if (idx >= total) return;
    int j = idx / NB;           // consecutive idx -> consecutive n -> coalesced x reads
    int n = idx - j * NB;
    int b = n / ENC_;
    int e = n - b * ENC_;
    const float* xb = x + (i64)b * SEQ_ * ENC_ + e;
    seg[(i64)n * s + j] = xb[(i64)(t * s + j) * ENC_] - xb[(i64)719 * ENC_];
}

// ---------------- fp32 NT GEMM: C[m,c] = act(sum_k A[m,k]*Bm[c,k] + bias[c]) -------------
// A:[M,K] rm, Bm:[Nc,K] rm, C:[M,Nc] rm. K chunks of 4 floats fully in/out of bounds
// (all K here are multiples of 4), so float4 loads need only chunk-level guards.
#define BM 64
#define BN 64
#define BK 16

template<bool RELU>
__global__ __launch_bounds__(256) void gemm_nt(const float* __restrict__ A,
                                               const float* __restrict__ Bm,
                                               const float* __restrict__ bias,
                                               float* __restrict__ C,
                                               int M, int Nc, int K) {
    __shared__ float As[BK][BM + 4];   // +4 keeps float4-aligned rows (68*4B % 16 == 0)
    __shared__ float Bs[BK][BN + 4];
    const int t = threadIdx.x;
    const int m0 = blockIdx.x * BM;
    const int n0 = blockIdx.y * BN;
    const int lrow = t >> 2;           // 0..63
    const int lk = (t & 3) << 2;       // 0,4,8,12
    const int tx = t & 15;
    const int ty = t >> 4;
    float acc[4][4] = {};
    for (int k0 = 0; k0 < K; k0 += BK) {
        int ak = k0 + lk;
        float4 av = make_float4(0.f, 0.f, 0.f, 0.f);
        int am = m0 + lrow;
        if (am < M && ak + 3 < K) av = *(const float4*)(A + (i64)am * K + ak);
        As[lk + 0][lrow] = av.x; As[lk + 1][lrow] = av.y;
        As[lk + 2][lrow] = av.z; As[lk + 3][lrow] = av.w;
        float4 bv = make_float4(0.f, 0.f, 0.f, 0.f);
        int bn = n0 + lrow;
        if (bn < Nc && ak + 3 < K) bv = *(const float4*)(Bm + (i64)bn * K + ak);
        Bs[lk + 0][lrow] = bv.x; Bs[lk + 1][lrow] = bv.y;
        Bs[lk + 2][lrow] = bv.z; Bs[lk + 3][lrow] = bv.w;
        __syncthreads();
#pragma unroll
        for (int kk = 0; kk < BK; ++kk) {
            float4 a4 = *(const float4*)&As[kk][ty << 2];
            float4 b4 = *(const float4*)&Bs[kk][tx << 2];
            float aa[4] = {a4.x, a4.y, a4.z, a4.w};
            float bb[4] = {b4.x, b4.y, b4.z, b4.w};
#pragma unroll
            for (int i = 0; i < 4; ++i)
#pragma unroll
                for (int j = 0; j < 4; ++j)
                    acc[i][j] += aa[i] * bb[j];
        }
        __syncthreads();
    }
#pragma unroll
    for (int i = 0; i < 4; ++i) {
        int m = m0 + (ty << 2) + i;
        if (m >= M) continue;
#pragma unroll
        for (int j = 0; j < 4; ++j) {
            int c = n0 + (tx << 2) + j;
            if (c >= Nc) continue;
            float v = acc[i][j] + bias[c];
            if (RELU) v = fmaxf(v, 0.0f);
            C[(i64)m * Nc + c] = v;
        }
    }
}

// GRU pointwise (encoder step, in-place h update)
__global__ __launch_bounds__(256) void gru_step(const float* __restrict__ gi,
                                                const float* __restrict__ gh,
                                                float* __restrict__ h,
                                                int rows, int d) {
    int idx = blockIdx.x * 256 + threadIdx.x;
    if (idx >= rows * d) return;
    int m = idx / d;
    int c = idx - m * d;
    i64 base = (i64)m * 3 * d + c;
    float ir = gi[base], iz = gi[base + d], inp = gi[base + 2 * d];
    float hr = gh[base], hz = gh[base + d], hn = gh[base + 2 * d];
    float r = sigmf(ir + hr);
    float z = sigmf(iz + hz);
    float nn = tanhf(inp + r * hn);
    h[idx] = (1.0f - z) * nn + z * h[idx];
}

// Decoder pointwise: hy[q,c], q = n*S + sy; gi row = e*S+sy (e = n%ENC), gh/h row = n
__global__ __launch_bounds__(256) void gru_dec(const float* __restrict__ gidec,
                                               const float* __restrict__ gh,
                                               const float* __restrict__ h,
                                               float* __restrict__ hy,
                                               int S, int d) {
    int idx = blockIdx.x * 256 + threadIdx.x;
    int total = S * NB * d;
    if (idx >= total) return;
    int q = idx / d;
    int c = idx - q * d;
    int n = q / S;
    int sy = q - n * S;
    int e = n % ENC_;
    i64 gib = (i64)(e * S + sy) * 3 * d + c;
    i64 ghb = (i64)n * 3 * d + c;
    float ir = gidec[gib], iz = gidec[gib + d], inp = gidec[gib + 2 * d];
    float hr = gh[ghb], hz = gh[ghb + d], hn = gh[ghb + 2 * d];
    float r = sigmf(ir + hr);
    float z = sigmf(iz + hz);
    float nn = tanhf(inp + r * hn);
    hy[idx] = (1.0f - z) * nn + z * h[(i64)n * d + c];
}

// pmat[(e*S+sy), c] = c < d/2 ? pos[sy, c] : chan[e, c-d/2]
__global__ __launch_bounds__(256) void pmat_fill(const float* __restrict__ pos,
                                                 const float* __restrict__ chan,
                                                 float* __restrict__ pmat,
                                                 int S, int d) {
    int idx = blockIdx.x * 256 + threadIdx.x;
    int total = ENC_ * S * d;
    if (idx >= total) return;
    int row = idx / d;
    int c = idx - row * d;
    int e = row / S;
    int sy = row - e * S;
    int half = d >> 1;
    pmat[idx] = (c < half) ? pos[sy * half + c] : chan[e * half + (c - half)];
}

// out[b,p,e] = x[b,719,e] + 0.5*(y0[n*96+p] + y1[n*96+p])
__global__ __launch_bounds__(256) void out_kernel(const float* __restrict__ x,
                                                  const float* __restrict__ y0,
                                                  const float* __restrict__ y1,
                                                  float* __restrict__ out) {
    int idx = blockIdx.x * 256 + threadIdx.x;
    const int total = BATCH_ * PRED_ * ENC_;
    if (idx >= total) return;
    int b = idx / (PRED_ * ENC_);
    int r = idx - b * (PRED_ * ENC_);
    int p = r / ENC_;
    int e = r - p * ENC_;
    int n = b * ENC_ + e;
    float sl = x[(i64)b * SEQ_ * ENC_ + (i64)719 * ENC_ + e];
    out[idx] = sl + 0.5f * (y0[(i64)n * PRED_ + p] + y1[(i64)n * PRED_ + p]);
}

extern "C" void kernel_launch(void* const* d_in, const int* in_sizes, int n_in,
                              void* d_out, int out_size, void* d_ws, size_t ws_size,
                              hipStream_t stream) {
    const float* x      = (const float*)d_in[0];
    const float* W_emb0 = (const float*)d_in[1];
    const float* b_emb0 = (const float*)d_in[2];
    const float* Wih0   = (const float*)d_in[3];
    const float* Whh0   = (const float*)d_in[4];
    const float* bih0   = (const float*)d_in[5];
    const float* bhh0   = (const float*)d_in[6];
    const float* Wpred0 = (const float*)d_in[7];
    const float* bpred0 = (const float*)d_in[8];
    const float* pos0   = (const float*)d_in[9];
    const float* chan0  = (const float*)d_in[10];
    const float* W_emb1 = (const float*)d_in[11];
    const float* b_emb1 = (const float*)d_in[12];
    const float* Wih1   = (const float*)d_in[13];
    const float* Whh1   = (const float*)d_in[14];
    const float* bih1   = (const float*)d_in[15];
    const float* bhh1   = (const float*)d_in[16];
    const float* Wpred1 = (const float*)d_in[17];
    const float* bpred1 = (const float*)d_in[18];
    const float* pos1   = (const float*)d_in[19];
    const float* chan1  = (const float*)d_in[20];
    float* out = (float*)d_out;

    // ---- workspace layout (floats) ----
    float* ws = (float*)d_ws;
    i64 off = 0;
    float* f_h    = ws + off; off += (i64)NB * 512;        // h (layer1 uses NB*256 prefix)
    float* f_xe   = ws + off; off += (i64)4 * NB * 256;    // xe_t / xe1[4 segs] / decoder hy
    float* f_gi   = ws + off; off += (i64)NB * 1536;       // gi_t / gi_dec
    float* f_gh   = ws + off; off += (i64)NB * 1536;       // gh_t / gh_dec
    float* f_seg  = ws + off; off += (i64)NB * 48;         // gathered segment
    float* f_pmat = ws + off; off += (i64)642 * 512;       // pos matrix (== 1284*256)
    float* f_y0   = ws + off; off += (i64)NB * 96;
    float* f_y1   = ws + off; off += (i64)NB * 96;
    i64 base_floats = off;
    float* f_gi1 = ws + off; off += (i64)4 * NB * 768;     // optional: layer1 gi, 4 segments
    i64 big_floats = off;
    bool pre_gi1 = ((i64)ws_size >= big_floats * 4);       // deterministic across calls

    auto gemm = [&](const float* A, const float* Bm, const float* bias, float* C,
                    int M, int Nc, int K, bool relu) {
        dim3 grid((M + BM - 1) / BM, (Nc + BN - 1) / BN);
        if (relu) gemm_nt<true><<<grid, 256, 0, stream>>>(A, Bm, bias, C, M, Nc, K);
        else      gemm_nt<false><<<grid, 256, 0, stream>>>(A, Bm, bias, C, M, Nc, K);
    };
    (void)base_floats;

    // ================= layer 0: d=512, s=48, T=15, S=2 =================
    zero_kernel<<<(NB * 512 + 255) / 256, 256, 0, stream>>>(f_h, NB * 512);
    for (int t = 0; t < 15; ++t) {
        seg_gather<<<(NB * 48 + 255) / 256, 256, 0, stream>>>(x, f_seg, t, 48);
        gemm(f_seg, W_emb0, b_emb0, f_xe, NB, 512, 48, true);        // xe_t = relu(...)
        gemm(f_xe, Wih0, bih0, f_gi, NB, 1536, 512, false);          // gi
        gemm(f_h,  Whh0, bhh0, f_gh, NB, 1536, 512, false);          // gh
        gru_step<<<(NB * 512 + 255) / 256, 256, 0, stream>>>(f_gi, f_gh, f_h, NB, 512);
    }
    // decoder 0
    pmat_fill<<<(ENC_ * 2 * 512 + 255) / 256, 256, 0, stream>>>(pos0, chan0, f_pmat, 2, 512);
    gemm(f_pmat, Wih0, bih0, f_gi, ENC_ * 2, 1536, 512, false);      // gi_dec [642,1536]
    gemm(f_h,    Whh0, bhh0, f_gh, NB, 1536, 512, false);            // gh_dec (shared over sy)
    {
        int tot = 2 * NB * 512;
        gru_dec<<<(tot + 255) / 256, 256, 0, stream>>>(f_gi, f_gh, f_h, f_xe, 2, 512);
    }
    gemm(f_xe, Wpred0, bpred0, f_y0, 2 * NB, 48, 512, false);        // y0 flat == [N,96]

    // ================= layer 1: d=256, s=24, S=4, 60 steps over segs t%4 =================
    zero_kernel<<<(NB * 256 + 255) / 256, 256, 0, stream>>>(f_h, NB * 256);
    for (int k = 0; k < 4; ++k) {
        seg_gather<<<(NB * 24 + 255) / 256, 256, 0, stream>>>(x, f_seg, k, 24);
        gemm(f_seg, W_emb1, b_emb1, f_xe + (i64)k * NB * 256, NB, 256, 24, true);
    }
    if (pre_gi1) {
        for (int k = 0; k < 4; ++k)
            gemm(f_xe + (i64)k * NB * 256, Wih1, bih1, f_gi1 + (i64)k * NB * 768,
                 NB, 768, 256, false);
    }
    for (int t = 0; t < 60; ++t) {
        const float* gi_t;
        if (pre_gi1) {
            gi_t = f_gi1 + (i64)(t & 3) * NB * 768;
        } else {
            gemm(f_xe + (i64)(t & 3) * NB * 256, Wih1, bih1, f_gi, NB, 768, 256, false);
            gi_t = f_gi;
        }
        gemm(f_h, Whh1, bhh1, f_gh, NB, 768, 256, false);
        gru_step<<<(NB * 256 + 255) / 256, 256, 0, stream>>>(gi_t, f_gh, f_h, NB, 256);
    }
    // decoder 1
    pmat_fill<<<(ENC_ * 4 * 256 + 255) / 256, 256, 0, stream>>>(pos1, chan1, f_pmat, 4, 256);
    gemm(f_pmat, Wih1, bih1, f_gi, ENC_ * 4, 768, 256, false);       // gi_dec [1284,768]
    gemm(f_h,    Whh1, bhh1, f_gh, NB, 768, 256, false);             // gh_dec
    {
        int tot = 4 * NB * 256;
        gru_dec<<<(tot + 255) / 256, 256, 0, stream>>>(f_gi, f_gh, f_h, f_xe, 4, 256);
    }
    gemm(f_xe, Wpred1, bpred1, f_y1, 4 * NB, 24, 256, false);        // y1 flat == [N,96]

    // ================= combine =================
    out_kernel<<<(BATCH_ * PRED_ * ENC_ + 255) / 256, 256, 0, stream>>>(x, f_y0, f_y1, out);
}

// Round 2
// 4021.767 us; speedup vs baseline: 4.2662x; 4.2662x over previous
//
#include <hip/hip_runtime.h>
#include <math.h>

// Hierarchical RNN — round 2: bf16 MFMA GEMMs + fused gh-GEMM/GRU step.
// N = B*ENC = 10272 rows (padded to MP=10368 = 81*128).
// layer0: 15 seq steps d=512; layer1: 60 seq steps d=256 (4 distinct gi segments).

#define NB     10272
#define MP     10368
#define ENC_   321
#define SEQ_   720
#define PRED_  96
#define BATCH_ 32

typedef long long i64;
typedef unsigned short u16;
using bf16x8 = __attribute__((ext_vector_type(8))) short;
using f32x4  = __attribute__((ext_vector_type(4))) float;

#define AS1 __attribute__((address_space(1)))
#define AS3 __attribute__((address_space(3)))
// async global->LDS, 16B per lane; dest = wave-uniform base + lane*16
#define GLOAD16(g, l) __builtin_amdgcn_global_load_lds((const AS1 void*)(g), (AS3 void*)(l), 16, 0, 0)

__device__ __forceinline__ float bf2f(u16 u) {
    union { unsigned i; float f; } v; v.i = ((unsigned)u) << 16; return v.f;
}
__device__ __forceinline__ u16 f2bf(float f) {
    union { float f; unsigned i; } v; v.f = f;
    unsigned r = (v.i + 0x7fff + ((v.i >> 16) & 1)) >> 16;
    return (u16)r;
}
__device__ __forceinline__ float sigf(float x) {
    x = fminf(fmaxf(x, -30.f), 30.f);
    return 1.f / (1.f + __expf(-x));
}
__device__ __forceinline__ float tanhfast(float x) {
    x = fminf(fmaxf(x, -15.f), 15.f);
    float e = __expf(2.f * x);
    return (e - 1.f) / (e + 1.f);
}

// ---------------------------------------------------------------- small utils
__global__ __launch_bounds__(256) void zero2_kernel(float* __restrict__ a,
                                                    u16* __restrict__ b, i64 n) {
    i64 i = (i64)blockIdx.x * 256 + threadIdx.x;
    if (i < n) { a[i] = 0.f; b[i] = 0; }
}

// fp32 -> bf16 with zero padding to [Rp][Cp]
__global__ __launch_bounds__(256) void convert_pad(const float* __restrict__ src,
                                                   u16* __restrict__ dst,
                                                   int R, int C, int Rp, int Cp) {
    i64 idx = (i64)blockIdx.x * 256 + threadIdx.x;
    i64 total = (i64)Rp * Cp;
    if (idx >= total) return;
    int r = (int)(idx / Cp);
    int c = (int)(idx - (i64)r * Cp);
    dst[idx] = (r < R && c < C) ? f2bf(src[(i64)r * C + c]) : (u16)0;
}

// seg[t][n][j] = bf16(x[b, (t0+t)*s + j, e] - x[b,719,e]); zero pad rows/cols
__global__ __launch_bounds__(256) void seg_gather_bf(const float* __restrict__ x,
                                                     u16* __restrict__ dst,
                                                     int t0, int T, int s, int Kp) {
    i64 idx = (i64)blockIdx.x * 256 + threadIdx.x;
    i64 per_t = (i64)MP * Kp;
    i64 total = (i64)T * per_t;
    if (idx >= total) return;
    int t = (int)(idx / per_t);
    i64 rem = idx - (i64)t * per_t;
    int j = (int)(rem / MP);
    int n = (int)(rem - (i64)j * MP);
    float v = 0.f;
    if (n < NB && j < s) {
        int b = n / ENC_, e = n - b * ENC_;
        const float* xb = x + (i64)b * SEQ_ * ENC_ + e;
        v = xb[(i64)((t0 + t) * s + j) * ENC_] - xb[(i64)(SEQ_ - 1) * ENC_];
    }
    dst[((i64)t * MP + n) * Kp + j] = f2bf(v);
}

// pmat[row][c] (bf16, rows padded to Rp): row=e*S+sy; c<d/2: pos[sy][c] else chan[e][c-d/2]
__global__ __launch_bounds__(256) void pmat_fill_bf(const float* __restrict__ pos,
                                                    const float* __restrict__ chan,
                                                    u16* __restrict__ dst,
                                                    int S, int d, int Rp) {
    i64 idx = (i64)blockIdx.x * 256 + threadIdx.x;
    i64 total = (i64)Rp * d;
    if (idx >= total) return;
    int row = (int)(idx / d);
    int c = (int)(idx - (i64)row * d);
    float v = 0.f;
    if (row < ENC_ * S) {
        int e = row / S, sy = row - e * S;
        int half = d >> 1;
        v = (c < half) ? pos[sy * half + c] : chan[e * half + (c - half)];
    }
    dst[idx] = f2bf(v);
}

// out[b,p,e] = x[b,719,e] + 0.5*(y0[n*96+p] + y1[n*96+p])
__global__ __launch_bounds__(256) void out_kernel(const float* __restrict__ x,
                                                  const float* __restrict__ y0,
                                                  const float* __restrict__ y1,
                                                  float* __restrict__ out) {
    int idx = blockIdx.x * 256 + threadIdx.x;
    const int total = BATCH_ * PRED_ * ENC_;
    if (idx >= total) return;
    int b = idx / (PRED_ * ENC_);
    int r = idx - b * (PRED_ * ENC_);
    int p = r / ENC_;
    int e = r - p * ENC_;
    int n = b * ENC_ + e;
    float sl = x[(i64)b * SEQ_ * ENC_ + (i64)(SEQ_ - 1) * ENC_ + e];
    out[idx] = sl + 0.5f * (y0[(i64)n * PRED_ + p] + y1[(i64)n * PRED_ + p]);
}

// ------------------------------------------------- bf16 MFMA NT GEMM 128x128xK
// C[m,c] = act(sum_k A[m,k]*B[c,k] + bias[c]); A rows padded (always readable),
// B rows padded to 128-mult. K mult of 64. LDS rows 128B, 16B chunks XOR-swizzled
// by (row&7) so ds_read_b128 spreads uniformly over all 8 bank groups.
template<bool RELU, bool OUTBF>
__global__ __launch_bounds__(256) void gemm_bf16mfma(const u16* __restrict__ A,
                                                     const u16* __restrict__ B,
                                                     const float* __restrict__ bias,
                                                     void* __restrict__ Cp,
                                                     int K, int Mstore, int Nstore,
                                                     int ldc) {
    __shared__ u16 smA[128 * 64];
    __shared__ u16 smB[128 * 64];
    const int tid = threadIdx.x;
    const int w = tid >> 6, l = tid & 63;
    const int m0 = blockIdx.x * 128, n0 = blockIdx.y * 128;
    const int srow = (l >> 3) & 7, pch = l & 7;
    const int cch = pch ^ srow;                  // logical chunk this lane fetches
    const u16* ga[4]; const u16* gb[4];
#pragma unroll
    for (int r = 0; r < 4; ++r) {
        int seg = r * 4 + w;
        ga[r] = A + (i64)(m0 + seg * 8 + srow) * K + cch * 8;
        gb[r] = B + (i64)(n0 + seg * 8 + srow) * K + cch * 8;
    }
    f32x4 acc[4][4] = {};
    const int lr = l & 15, lg = l >> 4;
    const int wm = (w >> 1) * 64, wn = (w & 1) * 64;
    for (int kk = 0; kk < K; kk += 64) {
#pragma unroll
        for (int r = 0; r < 4; ++r) { GLOAD16(ga[r], smA + (r * 4 + w) * 512); ga[r] += 64; }
#pragma unroll
        for (int r = 0; r < 4; ++r) { GLOAD16(gb[r], smB + (r * 4 + w) * 512); gb[r] += 64; }
        __syncthreads();
#pragma unroll
        for (int s = 0; s < 2; ++s) {
            const int ph = ((s * 4 + lg) ^ (lr & 7)) * 8;
            bf16x8 av[4], bv[4];
#pragma unroll
            for (int i = 0; i < 4; ++i)
                av[i] = *(const bf16x8*)(smA + (wm + i * 16 + lr) * 64 + ph);
#pragma unroll
            for (int j = 0; j < 4; ++j)
                bv[j] = *(const bf16x8*)(smB + (wn + j * 16 + lr) * 64 + ph);
#pragma unroll
            for (int i = 0; i < 4; ++i)
#pragma unroll
                for (int j = 0; j < 4; ++j)
                    acc[i][j] = __builtin_amdgcn_mfma_f32_16x16x32_bf16(av[i], bv[j], acc[i][j], 0, 0, 0);
        }
        __syncthreads();
    }
#pragma unroll
    for (int i = 0; i < 4; ++i) {
        int mbase = m0 + wm + i * 16 + 4 * lg;
#pragma unroll
        for (int j = 0; j < 4; ++j) {
            int c = n0 + wn + j * 16 + lr;
            if (c >= Nstore) continue;
            float bs = bias[c];
#pragma unroll
            for (int r = 0; r < 4; ++r) {
                int mm = mbase + r;
                if (mm < Mstore) {
                    float v = acc[i][j][r] + bs;
                    if (RELU) v = fmaxf(v, 0.f);
                    if (OUTBF) ((u16*)Cp)[(i64)mm * ldc + c] = f2bf(v);
                    else       ((float*)Cp)[(i64)mm * ldc + c] = v;
                }
            }
        }
    }
}

// ---------------------------------------- fused gh-GEMM + GRU pointwise
// Tile: 128 rows (m) x 64 outputs (c) x 3 gates. B rows {g*d + c0 + 0..63}.
// S==0: encoder — h[m,c] updated in place (fp32 + bf16 mirror).
// S>0 : decoder — for sy in 0..S-1 read gi_dec row (m%ENC)*S+sy, write hy bf16.
template<int S>
__global__ __launch_bounds__(256) void gru_fused(const u16* __restrict__ Abf,
                                                 const u16* __restrict__ Whh,
                                                 const float* __restrict__ bhh,
                                                 const u16* __restrict__ gi,
                                                 float* __restrict__ h,
                                                 u16* __restrict__ hbf,
                                                 u16* __restrict__ hy, int d) {
    __shared__ u16 smA[128 * 64];
    __shared__ u16 smB[3 * 64 * 64];
    const int tid = threadIdx.x;
    const int w = tid >> 6, l = tid & 63;
    const int m0 = blockIdx.x * 128;
    const int c0 = blockIdx.y * 64;
    const int srow = (l >> 3) & 7, pch = l & 7;
    const int cch = pch ^ srow;
    const u16* ga[4]; const u16* gb[6];
#pragma unroll
    for (int r = 0; r < 4; ++r)
        ga[r] = Abf + (i64)(m0 + (r * 4 + w) * 8 + srow) * d + cch * 8;
#pragma unroll
    for (int q = 0; q < 6; ++q) {
        int gs = q * 4 + w;
        int g = gs >> 3, sp = gs & 7;
        gb[q] = Whh + (i64)(g * d + c0 + sp * 8 + srow) * d + cch * 8;
    }
    f32x4 acc[3][4][2] = {};
    const int lr = l & 15, lg = l >> 4;
    const int wm = (w >> 1) * 64, wc = (w & 1) * 32;
    for (int kk = 0; kk < d; kk += 64) {
#pragma unroll
        for (int r = 0; r < 4; ++r) { GLOAD16(ga[r], smA + (r * 4 + w) * 512); ga[r] += 64; }
#pragma unroll
        for (int q = 0; q < 6; ++q) { GLOAD16(gb[q], smB + (q * 4 + w) * 512); gb[q] += 64; }
        __syncthreads();
#pragma unroll
        for (int s = 0; s < 2; ++s) {
            const int ph = ((s * 4 + lg) ^ (lr & 7)) * 8;
            bf16x8 av[4], bv[3][2];
#pragma unroll
            for (int i = 0; i < 4; ++i)
                av[i] = *(const bf16x8*)(smA + (wm + i * 16 + lr) * 64 + ph);
#pragma unroll
            for (int g = 0; g < 3; ++g)
#pragma unroll
                for (int j = 0; j < 2; ++j)
                    bv[g][j] = *(const bf16x8*)(smB + g * 4096 + (wc + j * 16 + lr) * 64 + ph);
#pragma unroll
            for (int g = 0; g < 3; ++g)
#pragma unroll
                for (int i = 0; i < 4; ++i)
#pragma unroll
                    for (int j = 0; j < 2; ++j)
                        acc[g][i][j] = __builtin_amdgcn_mfma_f32_16x16x32_bf16(av[i], bv[g][j], acc[g][i][j], 0, 0, 0);
        }
        __syncthreads();
    }
#pragma unroll
    for (int i = 0; i < 4; ++i) {
        int mbase = m0 + wm + i * 16 + 4 * lg;
#pragma unroll
        for (int j = 0; j < 2; ++j) {
            int cc = c0 + wc + j * 16 + lr;
            float b0 = bhh[cc], b1 = bhh[d + cc], b2 = bhh[2 * d + cc];
#pragma unroll
            for (int r = 0; r < 4; ++r) {
                int mm = mbase + r;
                if (mm >= NB) continue;
                float hr = acc[0][i][j][r] + b0;
                float hz = acc[1][i][j][r] + b1;
                float hn = acc[2][i][j][r] + b2;
                if constexpr (S == 0) {
                    i64 gib = (i64)mm * 3 * d + cc;
                    float rr = sigf(bf2f(gi[gib]) + hr);
                    float zz = sigf(bf2f(gi[gib + d]) + hz);
                    float nn = tanhfast(bf2f(gi[gib + 2 * d]) + rr * hn);
                    float ho = h[(i64)mm * d + cc];
                    float hnew = (1.f - zz) * nn + zz * ho;
                    h[(i64)mm * d + cc] = hnew;
                    hbf[(i64)mm * d + cc] = f2bf(hnew);
                } else {
                    int e = mm % ENC_;
                    float ho = h[(i64)mm * d + cc];
#pragma unroll
                    for (int sy = 0; sy < S; ++sy) {
                        i64 gib = (i64)(e * S + sy) * 3 * d + cc;
                        float rr = sigf(bf2f(gi[gib]) + hr);
                        float zz = sigf(bf2f(gi[gib + d]) + hz);
                        float nn = tanhfast(bf2f(gi[gib + 2 * d]) + rr * hn);
                        float v = (1.f - zz) * nn + zz * ho;
                        hy[((i64)mm * S + sy) * d + cc] = f2bf(v);
                    }
                }
            }
        }
    }
}

// ---------------------------------------------------------------- host
extern "C" void kernel_launch(void* const* d_in, const int* in_sizes, int n_in,
                              void* d_out, int out_size, void* d_ws, size_t ws_size,
                              hipStream_t stream) {
    const float* x      = (const float*)d_in[0];
    const float* W_emb0 = (const float*)d_in[1];
    const float* b_emb0 = (const float*)d_in[2];
    const float* Wih0   = (const float*)d_in[3];
    const float* Whh0   = (const float*)d_in[4];
    const float* bih0   = (const float*)d_in[5];
    const float* bhh0   = (const float*)d_in[6];
    const float* Wpred0 = (const float*)d_in[7];
    const float* bpred0 = (const float*)d_in[8];
    const float* pos0   = (const float*)d_in[9];
    const float* chan0  = (const float*)d_in[10];
    const float* W_emb1 = (const float*)d_in[11];
    const float* b_emb1 = (const float*)d_in[12];
    const float* Wih1   = (const float*)d_in[13];
    const float* Whh1   = (const float*)d_in[14];
    const float* bih1   = (const float*)d_in[15];
    const float* bhh1   = (const float*)d_in[16];
    const float* Wpred1 = (const float*)d_in[17];
    const float* bpred1 = (const float*)d_in[18];
    const float* pos1   = (const float*)d_in[19];
    const float* chan1  = (const float*)d_in[20];
    float* out = (float*)d_out;

    // ---- workspace carve (~180 MB; round-1 footprint of 200.5 MB proven available)
    i64 off = 0;
    char* base = (char*)d_ws;
    auto alloc = [&](i64 bytes) -> void* {
        void* p = base + off; off += (bytes + 255) & ~(i64)255; return p;
    };
    float* f_h   = (float*)alloc((i64)MP * 512 * 4);
    u16*   f_hbf = (u16*)  alloc((i64)MP * 512 * 2);
    u16*   f_gi0 = (u16*)  alloc((i64)MP * 1536 * 2);   // per-step gi / gi_dec
    u16*   f_xe  = (u16*)  alloc((i64)MP * 512 * 2);
    u16*   f_seg0= (u16*)  alloc((i64)MP * 64 * 2);
    u16*   f_seg1= (u16*)  alloc((i64)4 * MP * 64 * 2);
    u16*   f_xe1 = (u16*)  alloc((i64)4 * MP * 256 * 2);
    u16*   f_gi1 = (u16*)  alloc((i64)4 * MP * 768 * 2); // also decoder hy scratch
    u16*   f_pm0 = (u16*)  alloc((i64)768 * 512 * 2);
    u16*   f_pm1 = (u16*)  alloc((i64)1408 * 256 * 2);
    float* f_y0  = (float*)alloc((i64)20544 * 48 * 4);
    float* f_y1  = (float*)alloc((i64)41088 * 24 * 4);
    u16* wih0b = (u16*)alloc((i64)1536 * 512 * 2);
    u16* whh0b = (u16*)alloc((i64)1536 * 512 * 2);
    u16* wih1b = (u16*)alloc((i64)768 * 256 * 2);
    u16* whh1b = (u16*)alloc((i64)768 * 256 * 2);
    u16* we0b  = (u16*)alloc((i64)512 * 64 * 2);
    u16* we1b  = (u16*)alloc((i64)256 * 64 * 2);
    u16* wp0b  = (u16*)alloc((i64)128 * 512 * 2);
    u16* wp1b  = (u16*)alloc((i64)128 * 256 * 2);
    u16* f_hy  = f_gi1;   // decoder hy aliases gi1 (disjoint in time)

    auto cvt = [&](const float* s, u16* dst, int R, int C, int Rp, int Cp) {
        i64 tot = (i64)Rp * Cp;
        convert_pad<<<(int)((tot + 255) / 256), 256, 0, stream>>>(s, dst, R, C, Rp, Cp);
    };
    auto gemm = [&](const u16* A, const u16* B, const float* bias, void* C,
                    int Mtiles, int Nstore, int K, int Mstore, int ldc, int mode) {
        dim3 g(Mtiles, (Nstore + 127) / 128);
        if (mode == 0)      gemm_bf16mfma<false, false><<<g, 256, 0, stream>>>(A, B, bias, C, K, Mstore, Nstore, ldc);
        else if (mode == 1) gemm_bf16mfma<false, true ><<<g, 256, 0, stream>>>(A, B, bias, C, K, Mstore, Nstore, ldc);
        else                gemm_bf16mfma<true,  true ><<<g, 256, 0, stream>>>(A, B, bias, C, K, Mstore, Nstore, ldc);
    };

    // weight conversions (every call; graph-safe)
    cvt(Wih0, wih0b, 1536, 512, 1536, 512);
    cvt(Whh0, whh0b, 1536, 512, 1536, 512);
    cvt(Wih1, wih1b, 768, 256, 768, 256);
    cvt(Whh1, whh1b, 768, 256, 768, 256);
    cvt(W_emb0, we0b, 512, 48, 512, 64);
    cvt(W_emb1, we1b, 256, 24, 256, 64);
    cvt(Wpred0, wp0b, 48, 512, 128, 512);
    cvt(Wpred1, wp1b, 24, 256, 128, 256);
    {
        i64 t0 = (i64)768 * 512;
        pmat_fill_bf<<<(int)((t0 + 255) / 256), 256, 0, stream>>>(pos0, chan0, f_pm0, 2, 512, 768);
        i64 t1 = (i64)1408 * 256;
        pmat_fill_bf<<<(int)((t1 + 255) / 256), 256, 0, stream>>>(pos1, chan1, f_pm1, 4, 256, 1408);
    }

    // ================= layer 0: d=512, s=48, T=15, S=2 =================
    {
        i64 n = (i64)MP * 512;
        zero2_kernel<<<(int)((n + 255) / 256), 256, 0, stream>>>(f_h, f_hbf, n);
    }
    for (int t = 0; t < 15; ++t) {
        i64 tot = (i64)MP * 64;
        seg_gather_bf<<<(int)((tot + 255) / 256), 256, 0, stream>>>(x, f_seg0, t, 1, 48, 64);
        gemm(f_seg0, we0b, b_emb0, f_xe, 81, 512, 64, MP, 512, 2);       // xe = relu(...)
        gemm(f_xe, wih0b, bih0, f_gi0, 81, 1536, 512, NB, 1536, 1);      // gi (bf16)
        gru_fused<0><<<dim3(81, 8), 256, 0, stream>>>(f_hbf, whh0b, bhh0, f_gi0,
                                                      f_h, f_hbf, nullptr, 512);
    }
    // decoder 0
    gemm(f_pm0, wih0b, bih0, f_gi0, 6, 1536, 512, 642, 1536, 1);         // gi_dec
    gru_fused<2><<<dim3(81, 8), 256, 0, stream>>>(f_hbf, whh0b, bhh0, f_gi0,
                                                  f_h, nullptr, f_hy, 512);
    gemm(f_hy, wp0b, bpred0, f_y0, 161, 48, 512, 2 * NB, 48, 0);         // y0 = [N,96] flat

    // ================= layer 1: d=256, s=24, S=4, 60 steps over segs t%4 =====
    {
        i64 n = (i64)MP * 256;
        zero2_kernel<<<(int)((n + 255) / 256), 256, 0, stream>>>(f_h, f_hbf, n);
    }
    {
        i64 tot = (i64)4 * MP * 64;
        seg_gather_bf<<<(int)((tot + 255) / 256), 256, 0, stream>>>(x, f_seg1, 0, 4, 24, 64);
    }
    gemm(f_seg1, we1b, b_emb1, f_xe1, 324, 256, 64, 4 * MP, 256, 2);     // xe1 (4 segs)
    gemm(f_xe1, wih1b, bih1, f_gi1, 324, 768, 256, 4 * MP, 768, 1);      // gi1 (4 segs)
    for (int t = 0; t < 60; ++t) {
        gru_fused<0><<<dim3(81, 4), 256, 0, stream>>>(f_hbf, whh1b, bhh1,
                                                      f_gi1 + (i64)(t & 3) * MP * 768,
                                                      f_h, f_hbf, nullptr, 256);
    }
    // decoder 1
    gemm(f_pm1, wih1b, bih1, f_gi0, 11, 768, 256, 1284, 768, 1);         // gi_dec (gi0 buf)
    gru_fused<4><<<dim3(81, 4), 256, 0, stream>>>(f_hbf, whh1b, bhh1, f_gi0,
                                                  f_h, nullptr, f_hy, 256);
    gemm(f_hy, wp1b, bpred1, f_y1, 321, 24, 256, 4 * NB, 24, 0);         // y1 = [N,96] flat

    // ================= combine =================
    out_kernel<<<(BATCH_ * PRED_ * ENC_ + 255) / 256, 256, 0, stream>>>(x, f_y0, f_y1, out);
}